// Round 2
// baseline (4883.012 us; speedup 1.0000x reference)
//
#include <hip/hip_runtime.h>
#include <hip/hip_bf16.h>

typedef _Float16 f16;
typedef _Float16 f16x2 __attribute__((ext_vector_type(2)));
typedef _Float16 f16x4 __attribute__((ext_vector_type(4)));
typedef _Float16 f16x8 __attribute__((ext_vector_type(8)));

#define BATCH 128
#define SEQ   1024
#define IND   256
#define HID   512

#if defined(__has_builtin)
#if __has_builtin(__builtin_amdgcn_fdot2)
#define HAVE_FDOT2 1
#endif
#endif

__device__ __forceinline__ float fdot2(f16x2 a, f16x2 b, float c) {
#ifdef HAVE_FDOT2
  return __builtin_amdgcn_fdot2(a, b, c, false);
#else
  return c + (float)a[0] * (float)b[0] + (float)a[1] * (float)b[1];
#endif
}

union v8u {
  f16x8 v;
  f16x2 h[4];
};

__device__ __forceinline__ float tanh_fast(float s) {
  float e = __expf(2.0f * s);
  return 1.0f - 2.0f / (e + 1.0f);
}

// ---------------------------------------------------------------------------
// prep: W_su f32 [768][512] -> WzT f16 [h=512][k=512], WxT f16 [h=512][d=256]
// ---------------------------------------------------------------------------
__global__ __launch_bounds__(256) void prep_kernel(const float* __restrict__ Wsu,
                                                   f16* __restrict__ WzT,
                                                   f16* __restrict__ WxT) {
  int g = blockIdx.x * 256 + threadIdx.x;  // 0 .. 768*512-1
  int k = g >> 9;
  int h = g & 511;
  float v = Wsu[g];
  if (k < HID) WzT[h * HID + k] = (f16)v;
  else         WxT[h * IND + (k - HID)] = (f16)v;
}

// ---------------------------------------------------------------------------
// gemm1: xw[m][n] = sum_k x[m][k] * WxT[n][k] + bsu[n]   (f16 dot2, 64x64 tile)
// block 256 threads: cg=tid&15 -> 4 cols, rg=tid>>4 -> 4 rows, acc 4x4
// ---------------------------------------------------------------------------
__global__ __launch_bounds__(256) void gemm1_kernel(const float* __restrict__ x,
                                                    const f16* __restrict__ WxT,
                                                    const float* __restrict__ bsu,
                                                    f16* __restrict__ xw) {
  __shared__ __align__(16) f16x2 X2[16][64];  // [k-pair][row]
  __shared__ __align__(16) f16x2 W2[16][64];  // [k-pair][col]
  int m0 = blockIdx.x * 64, n0 = blockIdx.y * 64;
  int tid = threadIdx.x;
  int cg = tid & 15;
  int rg = tid >> 4;
  int sr = tid >> 2;
  int q  = tid & 3;

  float4 bv = *(const float4*)&bsu[n0 + cg * 4];
  float bj[4] = {bv.x, bv.y, bv.z, bv.w};
  float acc[4][4];
#pragma unroll
  for (int i = 0; i < 4; ++i)
#pragma unroll
    for (int j = 0; j < 4; ++j) acc[i][j] = bj[j];

  for (int ks = 0; ks < 8; ++ks) {
    int k0 = ks * 32;
    const float4* xp = (const float4*)&x[(m0 + sr) * IND + k0 + q * 8];
    float4 a0 = xp[0], a1 = xp[1];
    X2[q * 4 + 0][sr] = (f16x2){(f16)a0.x, (f16)a0.y};
    X2[q * 4 + 1][sr] = (f16x2){(f16)a0.z, (f16)a0.w};
    X2[q * 4 + 2][sr] = (f16x2){(f16)a1.x, (f16)a1.y};
    X2[q * 4 + 3][sr] = (f16x2){(f16)a1.z, (f16)a1.w};
    v8u wv;
    wv.v = *(const f16x8*)&WxT[(n0 + sr) * IND + k0 + q * 8];
#pragma unroll
    for (int p = 0; p < 4; ++p) W2[q * 4 + p][sr] = wv.h[p];
    __syncthreads();
#pragma unroll
    for (int kk = 0; kk < 16; ++kk) {
      v8u xv, wvv;
      xv.v = *(const f16x8*)&X2[kk][rg * 4];
      wvv.v = *(const f16x8*)&W2[kk][cg * 4];
#pragma unroll
      for (int i = 0; i < 4; ++i) {
        f16x2 xi = xv.h[i];
#pragma unroll
        for (int j = 0; j < 4; ++j) {
          acc[i][j] = fdot2(xi, wvv.h[j], acc[i][j]);
        }
      }
    }
    __syncthreads();
  }
#pragma unroll
  for (int i = 0; i < 4; ++i) {
    int row = m0 + rg * 4 + i;
    f16x4 o = {(f16)acc[i][0], (f16)acc[i][1], (f16)acc[i][2], (f16)acc[i][3]};
    *(f16x4*)&xw[row * HID + n0 + cg * 4] = o;
  }
}

// ---------------------------------------------------------------------------
// scan: 128 blocks (1 batch each) x 1024 threads.
// thread: wave w=tid>>6, lane l=tid&63, h_lo=l&7, kc=l>>3.
// owns 4 h rows (hbase..hbase+3) x 64-k chunk [kc*64, kc*64+64).
// W_z register-resident (128 f16x2). z broadcast via 1KB LDS (XOR-swizzled).
// kc reduction via 16KB LDS transpose; tanh dense on threads 0..511.
// ---------------------------------------------------------------------------
__global__ __launch_bounds__(1024) void scan_kernel(
    const f16* __restrict__ WzT, const f16* __restrict__ xw,
    const float* __restrict__ bsu, const float* __restrict__ carry,
    const float* __restrict__ Wout, const float* __restrict__ bout,
    float* __restrict__ outp) {
  __shared__ __align__(16) f16 zsh[512];
  __shared__ __align__(16) float part[8][512];

  int b = blockIdx.x;
  int tid = threadIdx.x;
  int w = tid >> 6, l = tid & 63;
  int h_lo = l & 7, kc = l >> 3;
  int hbase = w * 32 + h_lo * 4;
  int k0 = kc * 64;

  // one-time W_z load into registers
  f16x2 wreg[4][32];
#pragma unroll
  for (int j = 0; j < 4; ++j) {
    const f16* wp = &WzT[(hbase + j) * HID + k0];
#pragma unroll
    for (int s = 0; s < 8; ++s) {
      v8u v;
      v.v = *(const f16x8*)&wp[s * 8];
#pragma unroll
      for (int p = 0; p < 4; ++p) wreg[j][s * 4 + p] = v.h[p];
    }
  }

  float bsu_h = 0.f, wout_h = 0.f, xw_next = 0.f;
  if (tid < HID) {
    bsu_h = bsu[tid];
    wout_h = Wout[tid];
    float z0 = carry[b * HID + tid];
    int kcw = tid >> 6, sw = (tid >> 3) & 7, off = tid & 7;
    zsh[kcw * 64 + ((sw ^ kcw) & 7) * 8 + off] = (f16)z0;
    xw_next = (float)xw[(b * SEQ + 0) * HID + tid];
  }
  __syncthreads();

  float zlast = 0.f;
  for (int t = 0; t < SEQ; ++t) {
    // read my z chunk (swizzled slots -> conflict-free b128)
    v8u zc[8];
#pragma unroll
    for (int s = 0; s < 8; ++s)
      zc[s].v = *(const f16x8*)&zsh[k0 + ((s ^ kc) & 7) * 8];

    float acc0 = 0.f, acc1 = 0.f, acc2 = 0.f, acc3 = 0.f;
#pragma unroll
    for (int s = 0; s < 8; ++s) {
#pragma unroll
      for (int p = 0; p < 4; ++p) {
        f16x2 zp = zc[s].h[p];
        int pi = s * 4 + p;
        acc0 = fdot2(zp, wreg[0][pi], acc0);
        acc1 = fdot2(zp, wreg[1][pi], acc1);
        acc2 = fdot2(zp, wreg[2][pi], acc2);
        acc3 = fdot2(zp, wreg[3][pi], acc3);
      }
    }
    float4 av = {acc0, acc1, acc2, acc3};
    *(float4*)&part[kc][hbase] = av;
    __syncthreads();

    if (tid < HID) {
      float s = bsu_h + xw_next;
      if (t + 1 < SEQ) xw_next = (float)xw[(b * SEQ + t + 1) * HID + tid];
#pragma unroll
      for (int kcx = 0; kcx < 8; ++kcx) s += part[kcx][tid];
      float z = tanh_fast(s);
      int kcw = tid >> 6, sw2 = (tid >> 3) & 7, off = tid & 7;
      zsh[kcw * 64 + ((sw2 ^ kcw) & 7) * 8 + off] = (f16)z;
      zlast = z;
    }
    __syncthreads();
  }

  // outputs: z_last (f32) and out[b] = z_last . W_out + b_out
  if (tid < HID) {
    outp[BATCH + b * HID + tid] = zlast;
    part[0][tid] = zlast * wout_h;
  }
  __syncthreads();
  if (tid < 64) {
    float s2 = 0.f;
#pragma unroll
    for (int i = 0; i < 8; ++i) s2 += part[0][tid + 64 * i];
    part[1][tid] = s2;
  }
  __syncthreads();
  if (tid == 0) {
    float s3 = 0.f;
    for (int i = 0; i < 64; ++i) s3 += part[1][i];
    outp[b] = s3 + bout[0];
  }
}

// ---------------------------------------------------------------------------
extern "C" void kernel_launch(void* const* d_in, const int* in_sizes, int n_in,
                              void* d_out, int out_size, void* d_ws, size_t ws_size,
                              hipStream_t stream) {
  const float* x     = (const float*)d_in[0];
  const float* carry = (const float*)d_in[1];
  const float* Wsu   = (const float*)d_in[2];
  const float* bsu   = (const float*)d_in[3];
  const float* Wout  = (const float*)d_in[4];
  const float* bout  = (const float*)d_in[5];
  float* outp = (float*)d_out;

  char* ws = (char*)d_ws;
  f16* WzT = (f16*)(ws);                        // 512 KB
  f16* WxT = (f16*)(ws + 512 * 1024);           // 256 KB
  f16* xw  = (f16*)(ws + 768 * 1024);           // 128 MB (131072*512*2B)

  prep_kernel<<<dim3((768 * 512) / 256), 256, 0, stream>>>(Wsu, WzT, WxT);
  gemm1_kernel<<<dim3(BATCH * SEQ / 64, HID / 64), 256, 0, stream>>>(x, WxT, bsu, xw);
  scan_kernel<<<dim3(BATCH), 1024, 0, stream>>>(WzT, xw, bsu, carry, Wout, bout, outp);
}

// Round 3
// 4001.370 us; speedup vs baseline: 1.2203x; 1.2203x over previous
//
#include <hip/hip_runtime.h>
#include <hip/hip_bf16.h>

typedef _Float16 f16;
typedef _Float16 f16x2 __attribute__((ext_vector_type(2)));
typedef _Float16 f16x4 __attribute__((ext_vector_type(4)));
typedef _Float16 f16x8 __attribute__((ext_vector_type(8)));

#define BATCH 128
#define SEQ   1024
#define IND   256
#define HID   512

#if defined(__has_builtin)
#if __has_builtin(__builtin_amdgcn_fdot2)
#define HAVE_FDOT2 1
#endif
#endif

__device__ __forceinline__ float fdot2(f16x2 a, f16x2 b, float c) {
#ifdef HAVE_FDOT2
  return __builtin_amdgcn_fdot2(a, b, c, false);
#else
  return c + (float)a[0] * (float)b[0] + (float)a[1] * (float)b[1];
#endif
}

union v8u {
  f16x8 v;
  f16x2 h[4];
};

__device__ __forceinline__ float tanh_fast(float s) {
  float e = __expf(2.0f * s);
  return 1.0f - 2.0f / (e + 1.0f);
}

// ---------------------------------------------------------------------------
// prep: W_su f32 [768][512] -> WzT f16 [h=512][k=512], WxT f16 [h=512][d=256]
// ---------------------------------------------------------------------------
__global__ __launch_bounds__(256) void prep_kernel(const float* __restrict__ Wsu,
                                                   f16* __restrict__ WzT,
                                                   f16* __restrict__ WxT) {
  int g = blockIdx.x * 256 + threadIdx.x;  // 0 .. 768*512-1
  int k = g >> 9;
  int h = g & 511;
  float v = Wsu[g];
  if (k < HID) WzT[h * HID + k] = (f16)v;
  else         WxT[h * IND + (k - HID)] = (f16)v;
}

// ---------------------------------------------------------------------------
// gemm1: xw[m][n] = sum_k x[m][k] * WxT[n][k] + bsu[n]   (f16 dot2, 64x64 tile)
// ---------------------------------------------------------------------------
__global__ __launch_bounds__(256) void gemm1_kernel(const float* __restrict__ x,
                                                    const f16* __restrict__ WxT,
                                                    const float* __restrict__ bsu,
                                                    f16* __restrict__ xw) {
  __shared__ __align__(16) f16x2 X2[16][64];  // [k-pair][row]
  __shared__ __align__(16) f16x2 W2[16][64];  // [k-pair][col]
  int m0 = blockIdx.x * 64, n0 = blockIdx.y * 64;
  int tid = threadIdx.x;
  int cg = tid & 15;
  int rg = tid >> 4;
  int sr = tid >> 2;
  int q  = tid & 3;

  float4 bv = *(const float4*)&bsu[n0 + cg * 4];
  float bj[4] = {bv.x, bv.y, bv.z, bv.w};
  float acc[4][4];
#pragma unroll
  for (int i = 0; i < 4; ++i)
#pragma unroll
    for (int j = 0; j < 4; ++j) acc[i][j] = bj[j];

  for (int ks = 0; ks < 8; ++ks) {
    int k0 = ks * 32;
    const float4* xp = (const float4*)&x[(m0 + sr) * IND + k0 + q * 8];
    float4 a0 = xp[0], a1 = xp[1];
    X2[q * 4 + 0][sr] = (f16x2){(f16)a0.x, (f16)a0.y};
    X2[q * 4 + 1][sr] = (f16x2){(f16)a0.z, (f16)a0.w};
    X2[q * 4 + 2][sr] = (f16x2){(f16)a1.x, (f16)a1.y};
    X2[q * 4 + 3][sr] = (f16x2){(f16)a1.z, (f16)a1.w};
    v8u wv;
    wv.v = *(const f16x8*)&WxT[(n0 + sr) * IND + k0 + q * 8];
#pragma unroll
    for (int p = 0; p < 4; ++p) W2[q * 4 + p][sr] = wv.h[p];
    __syncthreads();
#pragma unroll
    for (int kk = 0; kk < 16; ++kk) {
      v8u xv, wvv;
      xv.v = *(const f16x8*)&X2[kk][rg * 4];
      wvv.v = *(const f16x8*)&W2[kk][cg * 4];
#pragma unroll
      for (int i = 0; i < 4; ++i) {
        f16x2 xi = xv.h[i];
#pragma unroll
        for (int j = 0; j < 4; ++j) {
          acc[i][j] = fdot2(xi, wvv.h[j], acc[i][j]);
        }
      }
    }
    __syncthreads();
  }
#pragma unroll
  for (int i = 0; i < 4; ++i) {
    int row = m0 + rg * 4 + i;
    f16x4 o = {(f16)acc[i][0], (f16)acc[i][1], (f16)acc[i][2], (f16)acc[i][3]};
    *(f16x4*)&xw[row * HID + n0 + cg * 4] = o;
  }
}

// ---------------------------------------------------------------------------
// scan: 128 blocks (1 batch each) x 1024 threads, 1 block/CU.
// thread: wave w=tid>>6, lane l=tid&63, h_lo=l&7, kc=l>>3.
// owns 4 h rows (hbase..hbase+3) x 64-k chunk [kc*64, kc*64+64).
// W_z register-resident (128 f16x2, pinned via asm opacity barrier).
// z broadcast via 1KB LDS (XOR-swizzled). kc reduction via 16KB LDS.
// ---------------------------------------------------------------------------
__global__ __launch_bounds__(1024, 4) void scan_kernel(
    const f16* __restrict__ WzT, const f16* __restrict__ xw,
    const float* __restrict__ bsu, const float* __restrict__ carry,
    const float* __restrict__ Wout, const float* __restrict__ bout,
    float* __restrict__ outp) {
  __shared__ __align__(16) f16 zsh[512];
  __shared__ __align__(16) float part[8][512];

  int b = blockIdx.x;
  int tid = threadIdx.x;
  int w = tid >> 6, l = tid & 63;
  int h_lo = l & 7, kc = l >> 3;
  int hbase = w * 32 + h_lo * 4;
  int k0 = kc * 64;

  // one-time W_z load into registers
  f16x2 wreg[4][32];
#pragma unroll
  for (int j = 0; j < 4; ++j) {
    const f16* wp = &WzT[(hbase + j) * HID + k0];
#pragma unroll
    for (int s = 0; s < 8; ++s) {
      v8u v;
      v.v = *(const f16x8*)&wp[s * 8];
#pragma unroll
      for (int p = 0; p < 4; ++p) wreg[j][s * 4 + p] = v.h[p];
    }
  }
  // opacity barrier: values can no longer be rematerialized as loads ->
  // compiler must keep them resident in VGPRs (budget 512/wave at 4 w/EU).
#pragma unroll
  for (int j = 0; j < 4; ++j) {
#pragma unroll
    for (int s = 0; s < 32; ++s) {
      unsigned u = __builtin_bit_cast(unsigned, wreg[j][s]);
      asm volatile("" : "+v"(u));
      wreg[j][s] = __builtin_bit_cast(f16x2, u);
    }
  }

  float bsu_h = 0.f, wout_h = 0.f, xw_next = 0.f;
  if (tid < HID) {
    bsu_h = bsu[tid];
    wout_h = Wout[tid];
    float z0 = carry[b * HID + tid];
    int kcw = tid >> 6, sw = (tid >> 3) & 7, off = tid & 7;
    zsh[kcw * 64 + ((sw ^ kcw) & 7) * 8 + off] = (f16)z0;
    xw_next = (float)xw[(b * SEQ + 0) * HID + tid];
  }
  __syncthreads();

  float zlast = 0.f;
  for (int t = 0; t < SEQ; ++t) {
    // read my z chunk (swizzled slots -> conflict-free b128)
    v8u zc[8];
#pragma unroll
    for (int s = 0; s < 8; ++s)
      zc[s].v = *(const f16x8*)&zsh[k0 + ((s ^ kc) & 7) * 8];

    float acc0 = 0.f, acc1 = 0.f, acc2 = 0.f, acc3 = 0.f;
#pragma unroll
    for (int s = 0; s < 8; ++s) {
#pragma unroll
      for (int p = 0; p < 4; ++p) {
        f16x2 zp = zc[s].h[p];
        int pi = s * 4 + p;
        acc0 = fdot2(zp, wreg[0][pi], acc0);
        acc1 = fdot2(zp, wreg[1][pi], acc1);
        acc2 = fdot2(zp, wreg[2][pi], acc2);
        acc3 = fdot2(zp, wreg[3][pi], acc3);
      }
    }
    float4 av = {acc0, acc1, acc2, acc3};
    *(float4*)&part[kc][hbase] = av;
    __syncthreads();

    if (tid < HID) {
      float s = bsu_h + xw_next;
      if (t + 1 < SEQ) xw_next = (float)xw[(b * SEQ + t + 1) * HID + tid];
#pragma unroll
      for (int kcx = 0; kcx < 8; ++kcx) s += part[kcx][tid];
      float z = tanh_fast(s);
      int kcw = tid >> 6, sw2 = (tid >> 3) & 7, off = tid & 7;
      zsh[kcw * 64 + ((sw2 ^ kcw) & 7) * 8 + off] = (f16)z;
      zlast = z;
    }
    __syncthreads();
  }

  // outputs: z_last (f32) and out[b] = z_last . W_out + b_out
  if (tid < HID) {
    outp[BATCH + b * HID + tid] = zlast;
    part[0][tid] = zlast * wout_h;
  }
  __syncthreads();
  if (tid < 64) {
    float s2 = 0.f;
#pragma unroll
    for (int i = 0; i < 8; ++i) s2 += part[0][tid + 64 * i];
    part[1][tid] = s2;
  }
  __syncthreads();
  if (tid == 0) {
    float s3 = 0.f;
    for (int i = 0; i < 64; ++i) s3 += part[1][i];
    outp[b] = s3 + bout[0];
  }
}

// ---------------------------------------------------------------------------
extern "C" void kernel_launch(void* const* d_in, const int* in_sizes, int n_in,
                              void* d_out, int out_size, void* d_ws, size_t ws_size,
                              hipStream_t stream) {
  const float* x     = (const float*)d_in[0];
  const float* carry = (const float*)d_in[1];
  const float* Wsu   = (const float*)d_in[2];
  const float* bsu   = (const float*)d_in[3];
  const float* Wout  = (const float*)d_in[4];
  const float* bout  = (const float*)d_in[5];
  float* outp = (float*)d_out;

  char* ws = (char*)d_ws;
  f16* WzT = (f16*)(ws);                        // 512 KB
  f16* WxT = (f16*)(ws + 512 * 1024);           // 256 KB
  f16* xw  = (f16*)(ws + 768 * 1024);           // 128 MB (131072*512*2B)

  prep_kernel<<<dim3((768 * 512) / 256), 256, 0, stream>>>(Wsu, WzT, WxT);
  gemm1_kernel<<<dim3(BATCH * SEQ / 64, HID / 64), 256, 0, stream>>>(x, WxT, bsu, xw);
  scan_kernel<<<dim3(BATCH), 1024, 0, stream>>>(WzT, xw, bsu, carry, Wout, bout, outp);
}

// Round 4
// 1993.309 us; speedup vs baseline: 2.4497x; 2.0074x over previous
//
#include <hip/hip_runtime.h>
#include <hip/hip_bf16.h>

typedef _Float16 f16;
typedef _Float16 f16x2 __attribute__((ext_vector_type(2)));
typedef _Float16 f16x4 __attribute__((ext_vector_type(4)));
typedef _Float16 f16x8 __attribute__((ext_vector_type(8)));

#define BATCH 128
#define SEQ   1024
#define IND   256
#define HID   512

#if defined(__has_builtin)
#if __has_builtin(__builtin_amdgcn_fdot2)
#define HAVE_FDOT2 1
#endif
#endif

__device__ __forceinline__ float fdot2(f16x2 a, f16x2 b, float c) {
#ifdef HAVE_FDOT2
  return __builtin_amdgcn_fdot2(a, b, c, false);
#else
  return c + (float)a[0] * (float)b[0] + (float)a[1] * (float)b[1];
#endif
}

union v8u {
  f16x8 v;
  f16x2 h[4];
};

__device__ __forceinline__ float tanh_fast(float s) {
  float e = __expf(2.0f * s);
  return 1.0f - 2.0f / (e + 1.0f);
}

// ---------------------------------------------------------------------------
// prep: W_su f32 [768][512] -> WzT f16 [h=512][k=512], WxT f16 [h=512][d=256]
// ---------------------------------------------------------------------------
__global__ __launch_bounds__(256) void prep_kernel(const float* __restrict__ Wsu,
                                                   f16* __restrict__ WzT,
                                                   f16* __restrict__ WxT) {
  int g = blockIdx.x * 256 + threadIdx.x;  // 0 .. 768*512-1
  int k = g >> 9;
  int h = g & 511;
  float v = Wsu[g];
  if (k < HID) WzT[h * HID + k] = (f16)v;
  else         WxT[h * IND + (k - HID)] = (f16)v;
}

// ---------------------------------------------------------------------------
// gemm1: xw[m][n] = sum_k x[m][k] * WxT[n][k] + bsu[n]   (f16 dot2, 64x64 tile)
// ---------------------------------------------------------------------------
__global__ __launch_bounds__(256) void gemm1_kernel(const float* __restrict__ x,
                                                    const f16* __restrict__ WxT,
                                                    const float* __restrict__ bsu,
                                                    f16* __restrict__ xw) {
  __shared__ __align__(16) f16x2 X2[16][64];  // [k-pair][row]
  __shared__ __align__(16) f16x2 W2[16][64];  // [k-pair][col]
  int m0 = blockIdx.x * 64, n0 = blockIdx.y * 64;
  int tid = threadIdx.x;
  int cg = tid & 15;
  int rg = tid >> 4;
  int sr = tid >> 2;
  int q  = tid & 3;

  float4 bv = *(const float4*)&bsu[n0 + cg * 4];
  float bj[4] = {bv.x, bv.y, bv.z, bv.w};
  float acc[4][4];
#pragma unroll
  for (int i = 0; i < 4; ++i)
#pragma unroll
    for (int j = 0; j < 4; ++j) acc[i][j] = bj[j];

  for (int ks = 0; ks < 8; ++ks) {
    int k0 = ks * 32;
    const float4* xp = (const float4*)&x[(m0 + sr) * IND + k0 + q * 8];
    float4 a0 = xp[0], a1 = xp[1];
    X2[q * 4 + 0][sr] = (f16x2){(f16)a0.x, (f16)a0.y};
    X2[q * 4 + 1][sr] = (f16x2){(f16)a0.z, (f16)a0.w};
    X2[q * 4 + 2][sr] = (f16x2){(f16)a1.x, (f16)a1.y};
    X2[q * 4 + 3][sr] = (f16x2){(f16)a1.z, (f16)a1.w};
    v8u wv;
    wv.v = *(const f16x8*)&WxT[(n0 + sr) * IND + k0 + q * 8];
#pragma unroll
    for (int p = 0; p < 4; ++p) W2[q * 4 + p][sr] = wv.h[p];
    __syncthreads();
#pragma unroll
    for (int kk = 0; kk < 16; ++kk) {
      v8u xv, wvv;
      xv.v = *(const f16x8*)&X2[kk][rg * 4];
      wvv.v = *(const f16x8*)&W2[kk][cg * 4];
#pragma unroll
      for (int i = 0; i < 4; ++i) {
        f16x2 xi = xv.h[i];
#pragma unroll
        for (int j = 0; j < 4; ++j) {
          acc[i][j] = fdot2(xi, wvv.h[j], acc[i][j]);
        }
      }
    }
    __syncthreads();
  }
#pragma unroll
  for (int i = 0; i < 4; ++i) {
    int row = m0 + rg * 4 + i;
    f16x4 o = {(f16)acc[i][0], (f16)acc[i][1], (f16)acc[i][2], (f16)acc[i][3]};
    *(f16x4*)&xw[row * HID + n0 + cg * 4] = o;
  }
}

// ---------------------------------------------------------------------------
// scan: 128 blocks (1 batch each) x 1024 threads (16 waves, 4/SIMD).
// thread: wave w=tid>>6, lane l=tid&63, h_lo=l&7, kc=l>>3.
// owns 4 h rows (hbase..hbase+3) x 64-k chunk [kc*64, kc*64+64).
// Residency plan (hard cap 128 VGPR/thread at 16 waves/CU):
//   rows 0..2: 96 f16x2 in VGPRs (96 regs)  -- fits with ~25 regs of state
//   row  3   : in LDS, layout [s][tid] f16x8 -> conflict-free ds_read_b128
// z broadcast via 1KB LDS (XOR-swizzled, 8-lane same-address broadcast).
// kc reduction via 16KB LDS; tanh dense on threads 0..511.
// ---------------------------------------------------------------------------
__global__ __launch_bounds__(1024, 4) void scan_kernel(
    const f16* __restrict__ WzT, const f16* __restrict__ xw,
    const float* __restrict__ bsu, const float* __restrict__ carry,
    const float* __restrict__ Wout, const float* __restrict__ bout,
    float* __restrict__ outp) {
  __shared__ __align__(16) f16 zsh[512];           // 1 KB
  __shared__ __align__(16) f16x8 wl[8][1024];      // 128 KB: row-3 weights
  __shared__ __align__(16) float part[8][512];     // 16 KB

  int b = blockIdx.x;
  int tid = threadIdx.x;
  int w = tid >> 6, l = tid & 63;
  int h_lo = l & 7, kc = l >> 3;
  int hbase = w * 32 + h_lo * 4;
  int k0 = kc * 64;

  // rows 0..2 of this thread's W_z tile -> registers
  f16x2 wreg[3][32];
#pragma unroll
  for (int j = 0; j < 3; ++j) {
    const f16* wp = &WzT[(hbase + j) * HID + k0];
#pragma unroll
    for (int s = 0; s < 8; ++s) {
      v8u v;
      v.v = *(const f16x8*)&wp[s * 8];
#pragma unroll
      for (int p = 0; p < 4; ++p) wreg[j][s * 4 + p] = v.h[p];
    }
  }
  // opacity barrier: prevent remat/sinking of the register-resident rows
#pragma unroll
  for (int j = 0; j < 3; ++j) {
#pragma unroll
    for (int s = 0; s < 32; ++s) {
      unsigned u = __builtin_bit_cast(unsigned, wreg[j][s]);
      asm volatile("" : "+v"(u));
      wreg[j][s] = __builtin_bit_cast(f16x2, u);
    }
  }
  // row 3 -> LDS, [s][tid] so a wave's read s is contiguous 1KB
  {
    const f16* wp3 = &WzT[(hbase + 3) * HID + k0];
#pragma unroll
    for (int s = 0; s < 8; ++s) wl[s][tid] = *(const f16x8*)&wp3[s * 8];
  }

  float bsu_h = 0.f, xw_next = 0.f;
  if (tid < HID) {
    bsu_h = bsu[tid];
    float z0 = carry[b * HID + tid];
    int kcw = tid >> 6, sw = (tid >> 3) & 7, off = tid & 7;
    zsh[kcw * 64 + ((sw ^ kcw) & 7) * 8 + off] = (f16)z0;
    xw_next = (float)xw[(b * SEQ + 0) * HID + tid];
  }
  __syncthreads();

  float zlast = 0.f;
  for (int t = 0; t < SEQ; ++t) {
    float acc0 = 0.f, acc1 = 0.f, acc2 = 0.f, acc3 = 0.f;
#pragma unroll
    for (int s = 0; s < 8; ++s) {
      v8u zc, wv;
      zc.v = *(const f16x8*)&zsh[k0 + ((s ^ kc) & 7) * 8];
      wv.v = wl[s][tid];
#pragma unroll
      for (int p = 0; p < 4; ++p) {
        f16x2 zp = zc.h[p];
        int pi = s * 4 + p;
        acc0 = fdot2(zp, wreg[0][pi], acc0);
        acc1 = fdot2(zp, wreg[1][pi], acc1);
        acc2 = fdot2(zp, wreg[2][pi], acc2);
        acc3 = fdot2(zp, wv.h[p], acc3);
      }
    }
    float4 av = {acc0, acc1, acc2, acc3};
    *(float4*)&part[kc][hbase] = av;
    __syncthreads();

    if (tid < HID) {
      float s = bsu_h + xw_next;
      if (t + 1 < SEQ) xw_next = (float)xw[(b * SEQ + t + 1) * HID + tid];
#pragma unroll
      for (int kcx = 0; kcx < 8; ++kcx) s += part[kcx][tid];
      float z = tanh_fast(s);
      int kcw = tid >> 6, sw2 = (tid >> 3) & 7, off = tid & 7;
      zsh[kcw * 64 + ((sw2 ^ kcw) & 7) * 8 + off] = (f16)z;
      zlast = z;
    }
    __syncthreads();
  }

  // outputs: z_last (f32) and out[b] = z_last . W_out + b_out
  if (tid < HID) {
    outp[BATCH + b * HID + tid] = zlast;
    part[0][tid] = zlast * Wout[tid];
  }
  __syncthreads();
  if (tid < 64) {
    float s2 = 0.f;
#pragma unroll
    for (int i = 0; i < 8; ++i) s2 += part[0][tid + 64 * i];
    part[1][tid] = s2;
  }
  __syncthreads();
  if (tid == 0) {
    float s3 = 0.f;
    for (int i = 0; i < 64; ++i) s3 += part[1][i];
    outp[b] = s3 + bout[0];
  }
}

// ---------------------------------------------------------------------------
extern "C" void kernel_launch(void* const* d_in, const int* in_sizes, int n_in,
                              void* d_out, int out_size, void* d_ws, size_t ws_size,
                              hipStream_t stream) {
  const float* x     = (const float*)d_in[0];
  const float* carry = (const float*)d_in[1];
  const float* Wsu   = (const float*)d_in[2];
  const float* bsu   = (const float*)d_in[3];
  const float* Wout  = (const float*)d_in[4];
  const float* bout  = (const float*)d_in[5];
  float* outp = (float*)d_out;

  char* ws = (char*)d_ws;
  f16* WzT = (f16*)(ws);                        // 512 KB
  f16* WxT = (f16*)(ws + 512 * 1024);           // 256 KB
  f16* xw  = (f16*)(ws + 768 * 1024);           // 128 MB (131072*512*2B)

  prep_kernel<<<dim3((768 * 512) / 256), 256, 0, stream>>>(Wsu, WzT, WxT);
  gemm1_kernel<<<dim3(BATCH * SEQ / 64, HID / 64), 256, 0, stream>>>(x, WxT, bsu, xw);
  scan_kernel<<<dim3(BATCH), 1024, 0, stream>>>(WzT, xw, bsu, carry, Wout, bout, outp);
}